// Round 1
// baseline (362.753 us; speedup 1.0000x reference)
//
#include <hip/hip_runtime.h>
#include <hip/hip_bf16.h>
#include <stdint.h>

#define NB 16
#define NS 1024
#define ND 512
#define NO 512
#define NROW (NB*NS)   // 16384

typedef float f32x4 __attribute__((ext_vector_type(4)));
typedef __bf16 bf16x8 __attribute__((ext_vector_type(8)));

__device__ inline unsigned short f2bs(float f) {
  union { __hip_bfloat16 h; unsigned short u; } c;
  c.h = __float2bfloat16(f);
  return c.u;
}

// ---------------- K1a: row sum-of-squares -> rnorm, cast x -> bf16 ----------------
__global__ __launch_bounds__(64) void k_prep_x(const float* __restrict__ x,
                                               __hip_bfloat16* __restrict__ xb,
                                               float* __restrict__ rnorm) {
  int row = blockIdx.x;
  int lane = threadIdx.x;
  const float* xr = x + (size_t)row * ND;
  float4 v0 = ((const float4*)xr)[lane*2 + 0];
  float4 v1 = ((const float4*)xr)[lane*2 + 1];
  float vals[8] = {v0.x,v0.y,v0.z,v0.w,v1.x,v1.y,v1.z,v1.w};
  float ssq = 0.f;
  #pragma unroll
  for (int k=0;k<8;++k) ssq = fmaf(vals[k], vals[k], ssq);
  #pragma unroll
  for (int off=32; off>0; off>>=1) ssq += __shfl_xor(ssq, off, 64);
  union { unsigned short us[8]; uint4 q; } pk;
  #pragma unroll
  for (int k=0;k<8;++k) pk.us[k] = f2bs(vals[k]);
  ((uint4*)(xb + (size_t)row*ND))[lane] = pk.q;
  if (lane == 0) rnorm[row] = 1.0f / fmaxf(sqrtf(ssq), 1e-12f);
}

// ---------------- K1b: Wt[o][d] = bf16(W[d][o]) ----------------
__global__ __launch_bounds__(1024) void k_prep_w(const float* __restrict__ W,
                                                 __hip_bfloat16* __restrict__ Wt) {
  __shared__ float tile[32][33];
  int o0 = blockIdx.x*32, d0 = blockIdx.y*32;
  int tx = threadIdx.x, ty = threadIdx.y;
  tile[ty][tx] = W[(size_t)(d0+ty)*NO + o0+tx];
  __syncthreads();
  Wt[(size_t)(o0+ty)*ND + d0+tx] = __float2bfloat16(tile[tx][ty]);
}

// ---------------- K2: ht[o][i] = sum_d Wt[o][d]*xb[i][d]  (MFMA bf16) ----------------
// M=512 (o, blockIdx.y), N=16384 (i, blockIdx.x), K=512. 128x128 tile, BK=64, 4 waves 2x2.
__global__ __launch_bounds__(256) void k_gemm_ht(const __hip_bfloat16* __restrict__ Wt,
                                                 const __hip_bfloat16* __restrict__ xb,
                                                 __hip_bfloat16* __restrict__ ht) {
  __shared__ __hip_bfloat16 At[128*64];
  __shared__ __hip_bfloat16 Bt[128*64];
  int m0 = blockIdx.y*128, n0 = blockIdx.x*128;
  int tid = threadIdx.x;
  int wid = tid>>6, lane = tid&63;
  int wm = (wid>>1)*64, wn = (wid&1)*64;
  f32x4 acc[4][4] = {};
  for (int k0 = 0; k0 < ND; k0 += 64) {
    __syncthreads();
    int r = tid>>3, cb = (tid&7)*8;
    #pragma unroll
    for (int p=0; p<4; ++p) {
      int rr = r + p*32;
      *(uint4*)&At[rr*64 + cb] = *(const uint4*)&Wt[(size_t)(m0+rr)*ND + k0+cb];
      *(uint4*)&Bt[rr*64 + cb] = *(const uint4*)&xb[(size_t)(n0+rr)*ND + k0+cb];
    }
    __syncthreads();
    #pragma unroll
    for (int kk=0; kk<64; kk+=32) {
      bf16x8 af[4], bfr[4];
      int rowA = wm + (lane&15);
      int rowB = wn + (lane&15);
      int colk = kk + ((lane>>4)<<3);
      #pragma unroll
      for (int mi=0; mi<4; ++mi) af[mi]  = *(const bf16x8*)&At[(rowA+mi*16)*64 + colk];
      #pragma unroll
      for (int ni=0; ni<4; ++ni) bfr[ni] = *(const bf16x8*)&Bt[(rowB+ni*16)*64 + colk];
      #pragma unroll
      for (int mi=0; mi<4; ++mi)
        #pragma unroll
        for (int ni=0; ni<4; ++ni)
          acc[mi][ni] = __builtin_amdgcn_mfma_f32_16x16x32_bf16(af[mi], bfr[ni], acc[mi][ni], 0,0,0);
    }
  }
  int rbase = (lane>>4)*4, col = lane&15;
  #pragma unroll
  for (int mi=0; mi<4; ++mi)
    #pragma unroll
    for (int ni=0; ni<4; ++ni) {
      int gm = m0 + wm + mi*16 + rbase;
      int gn = n0 + wn + ni*16 + col;
      #pragma unroll
      for (int r2=0; r2<4; ++r2)
        ht[(size_t)(gm+r2)*NROW + gn] = __float2bfloat16(acc[mi][ni][r2]);
    }
}

// ---------------- K3: a_src[i], a_dst[i] from ht columns ----------------
__global__ __launch_bounds__(256) void k_logits(const __hip_bfloat16* __restrict__ ht,
                                                const float* __restrict__ att_src,
                                                const float* __restrict__ att_dst,
                                                float* __restrict__ a_src,
                                                float* __restrict__ a_dst) {
  int i = blockIdx.x*256 + threadIdx.x;
  float s = 0.f, d = 0.f;
  for (int o=0; o<NO; ++o) {
    float hv = __bfloat162float(ht[(size_t)o*NROW + i]);
    s = fmaf(hv, att_src[o], s);
    d = fmaf(hv, att_dst[o], d);
  }
  a_src[i] = s;
  a_dst[i] = d;
}

// ---------------- K4: f32 sim over lower-tri 64x64 tile pairs -> E (bf16 logits) ----------------
__global__ __launch_bounds__(256) void k_sim(const float* __restrict__ x,
                                             const float* __restrict__ rnorm,
                                             const float* __restrict__ a_src,
                                             const float* __restrict__ a_dst,
                                             __hip_bfloat16* __restrict__ E) {
  int tj = blockIdx.x, ti = blockIdx.y, b = blockIdx.z;
  if (tj > ti) return;
  __shared__ float xdT[64][68];
  __shared__ float xsT[64][68];
  int tid = threadIdx.x;
  float acc[4][4] = {};
  const float* xb_ = x + (size_t)b*NS*ND;
  for (int kc=0; kc<ND; kc+=64) {
    __syncthreads();
    int rr = tid>>4, c0 = (tid&15)*4;
    #pragma unroll
    for (int p=0; p<4; ++p) {
      int r = rr + p*16;
      float4 vd = *(const float4*)&xb_[(size_t)(ti*64+r)*ND + kc + c0];
      float4 vs = *(const float4*)&xb_[(size_t)(tj*64+r)*ND + kc + c0];
      xdT[c0+0][r]=vd.x; xdT[c0+1][r]=vd.y; xdT[c0+2][r]=vd.z; xdT[c0+3][r]=vd.w;
      xsT[c0+0][r]=vs.x; xsT[c0+1][r]=vs.y; xsT[c0+2][r]=vs.z; xsT[c0+3][r]=vs.w;
    }
    __syncthreads();
    int ty4 = (tid>>4)*4, tx4 = (tid&15)*4;
    #pragma unroll 4
    for (int kk=0; kk<64; ++kk) {
      float4 a  = *(const float4*)&xdT[kk][ty4];
      float4 bv = *(const float4*)&xsT[kk][tx4];
      float av[4] = {a.x,a.y,a.z,a.w};
      float bw[4] = {bv.x,bv.y,bv.z,bv.w};
      #pragma unroll
      for (int i2=0;i2<4;++i2)
        #pragma unroll
        for (int j2=0;j2<4;++j2)
          acc[i2][j2] = fmaf(av[i2], bw[j2], acc[i2][j2]);
    }
  }
  int ty4 = (tid>>4)*4, tx4 = (tid&15)*4;
  #pragma unroll
  for (int i2=0;i2<4;++i2) {
    int t_g = ti*64 + ty4 + i2;
    int git = b*NS + t_g;
    float rnt = rnorm[git];
    float adv = a_dst[git];
    #pragma unroll
    for (int j2=0;j2<4;++j2) {
      int s_g = tj*64 + tx4 + j2;
      int gis = b*NS + s_g;
      float sim = acc[i2][j2] * rnt * rnorm[gis];
      bool edge = (s_g == t_g) || (s_g < t_g && sim > 0.9f);
      float v = adv + a_src[gis];
      float e = (v > 0.f) ? v : 0.2f*v;
      E[(size_t)git*NS + s_g] = edge ? __float2bfloat16(e) : __float2bfloat16(-INFINITY);
    }
  }
}

// ---------------- K5: per-row masked softmax in place, zero-fill to 128-boundary ----------------
__global__ __launch_bounds__(256) void k_softmax(__hip_bfloat16* __restrict__ E) {
  int rowid = blockIdx.x;           // b*NS + t
  int t = rowid & (NS-1);
  __hip_bfloat16* Erow = E + (size_t)rowid * NS;
  int tid = threadIdx.x;
  int n = t + 1;
  float v[4];
  float lm = -INFINITY;
  #pragma unroll
  for (int k=0;k<4;++k) {
    int s = tid + k*256;
    v[k] = (s < n) ? __bfloat162float(Erow[s]) : -INFINITY;
    lm = fmaxf(lm, v[k]);
  }
  __shared__ float red1[4];
  __shared__ float red2[4];
  #pragma unroll
  for (int off=32; off>0; off>>=1) lm = fmaxf(lm, __shfl_xor(lm, off, 64));
  int wid = tid>>6, lane = tid&63;
  if (lane==0) red1[wid] = lm;
  __syncthreads();
  float m = fmaxf(fmaxf(red1[0],red1[1]), fmaxf(red1[2],red1[3]));
  float ls = 0.f;
  #pragma unroll
  for (int k=0;k<4;++k) {
    int s = tid + k*256;
    if (s < n) ls += __expf(v[k] - m);
  }
  #pragma unroll
  for (int off=32; off>0; off>>=1) ls += __shfl_xor(ls, off, 64);
  if (lane==0) red2[wid] = ls;
  __syncthreads();
  float l = red2[0]+red2[1]+red2[2]+red2[3];
  float inv = 1.0f / l;
  #pragma unroll
  for (int k=0;k<4;++k) {
    int s = tid + k*256;
    if (s < n) Erow[s] = __float2bfloat16(__expf(v[k] - m) * inv);
  }
  int end = ((t >> 7) + 1) << 7;
  for (int s = n + tid; s < end; s += 256) Erow[s] = __float2bfloat16(0.0f);
}

// ---------------- K6: out = relu(P @ h + bias), causal K extent ----------------
// grid (nt=4, mt=8, b=16); A = P[b] rows t (stride NS), B^T = ht rows o (stride NROW, col b*NS+k)
__global__ __launch_bounds__(256) void k_pv(const __hip_bfloat16* __restrict__ P,
                                            const __hip_bfloat16* __restrict__ ht,
                                            const float* __restrict__ bias,
                                            float* __restrict__ out) {
  int nt = blockIdx.x, mt = blockIdx.y, b = blockIdx.z;
  int m0 = mt*128, n0 = nt*128;
  int Kext = (mt+1)*128;
  __shared__ __hip_bfloat16 At[128*64];
  __shared__ __hip_bfloat16 Bt[128*64];
  const __hip_bfloat16* Pb = P + (size_t)b*NS*NS;
  int tid = threadIdx.x;
  int wid = tid>>6, lane = tid&63;
  int wm = (wid>>1)*64, wn = (wid&1)*64;
  f32x4 acc[4][4] = {};
  for (int k0 = 0; k0 < Kext; k0 += 64) {
    __syncthreads();
    int r = tid>>3, cb = (tid&7)*8;
    #pragma unroll
    for (int p=0; p<4; ++p) {
      int rr = r + p*32;
      *(uint4*)&At[rr*64 + cb] = *(const uint4*)&Pb[(size_t)(m0+rr)*NS + k0+cb];
      *(uint4*)&Bt[rr*64 + cb] = *(const uint4*)&ht[(size_t)(n0+rr)*NROW + b*NS + k0+cb];
    }
    __syncthreads();
    #pragma unroll
    for (int kk=0; kk<64; kk+=32) {
      bf16x8 af[4], bfr[4];
      int rowA = wm + (lane&15);
      int rowB = wn + (lane&15);
      int colk = kk + ((lane>>4)<<3);
      #pragma unroll
      for (int mi=0; mi<4; ++mi) af[mi]  = *(const bf16x8*)&At[(rowA+mi*16)*64 + colk];
      #pragma unroll
      for (int ni=0; ni<4; ++ni) bfr[ni] = *(const bf16x8*)&Bt[(rowB+ni*16)*64 + colk];
      #pragma unroll
      for (int mi=0; mi<4; ++mi)
        #pragma unroll
        for (int ni=0; ni<4; ++ni)
          acc[mi][ni] = __builtin_amdgcn_mfma_f32_16x16x32_bf16(af[mi], bfr[ni], acc[mi][ni], 0,0,0);
    }
  }
  int rbase = (lane>>4)*4, col = lane&15;
  #pragma unroll
  for (int mi=0; mi<4; ++mi)
    #pragma unroll
    for (int ni=0; ni<4; ++ni) {
      int gm = m0 + wm + mi*16 + rbase;   // t (local)
      int gn = n0 + wn + ni*16 + col;     // o
      float bv = bias[gn];
      #pragma unroll
      for (int r2=0; r2<4; ++r2)
        out[((size_t)b*NS + gm + r2)*NO + gn] = fmaxf(acc[mi][ni][r2] + bv, 0.0f);
    }
}

extern "C" void kernel_launch(void* const* d_in, const int* in_sizes, int n_in,
                              void* d_out, int out_size, void* d_ws, size_t ws_size,
                              hipStream_t stream) {
  (void)in_sizes; (void)n_in; (void)out_size; (void)ws_size;
  const float* x       = (const float*)d_in[0];
  const float* W       = (const float*)d_in[1];
  const float* att_src = (const float*)d_in[2];
  const float* att_dst = (const float*)d_in[3];
  const float* bias    = (const float*)d_in[4];
  float* out = (float*)d_out;

  char* ws = (char*)d_ws;
  __hip_bfloat16* xb    = (__hip_bfloat16*)(ws + 0);          // 16,777,216 B
  __hip_bfloat16* Wt    = (__hip_bfloat16*)(ws + 16777216);   //    524,288 B
  __hip_bfloat16* ht    = (__hip_bfloat16*)(ws + 17301504);   // 16,777,216 B
  float*          rnorm = (float*)        (ws + 34078720);    //     65,536 B
  float*          a_src = (float*)        (ws + 34144256);    //     65,536 B
  float*          a_dst = (float*)        (ws + 34209792);    //     65,536 B
  __hip_bfloat16* E     = (__hip_bfloat16*)(ws + 34275328);   // 33,554,432 B (end ~67.8 MB)

  k_prep_x <<<dim3(NROW),     dim3(64),    0, stream>>>(x, xb, rnorm);
  k_prep_w <<<dim3(16,16),    dim3(32,32), 0, stream>>>(W, Wt);
  k_gemm_ht<<<dim3(128,4),    dim3(256),   0, stream>>>(Wt, xb, ht);
  k_logits <<<dim3(64),       dim3(256),   0, stream>>>(ht, att_src, att_dst, a_src, a_dst);
  k_sim    <<<dim3(16,16,16), dim3(256),   0, stream>>>(x, rnorm, a_src, a_dst, E);
  k_softmax<<<dim3(NROW),     dim3(256),   0, stream>>>(E);
  k_pv     <<<dim3(4,8,16),   dim3(256),   0, stream>>>(E, ht, bias, out);
}

// Round 3
// 234.802 us; speedup vs baseline: 1.5449x; 1.5449x over previous
//
#include <hip/hip_runtime.h>
#include <hip/hip_bf16.h>
#include <stdint.h>

#define NB 16
#define NS 1024
#define ND 512
#define NO 512
#define NROW (NB*NS)   // 16384
#define SIM_BAND 2e-3f
#define LIST_CAP (2*1024*1024)

typedef float f32x4 __attribute__((ext_vector_type(4)));
typedef __bf16 bf16x8 __attribute__((ext_vector_type(8)));

__device__ inline unsigned short f2bs(float f) {
  union { __hip_bfloat16 h; unsigned short u; } c;
  c.h = __float2bfloat16(f);
  return c.u;
}

// split y into bf16 hi + bf16 lo (y ~= hi + lo, ~16 mantissa bits)
__device__ inline void split_pack(float y, unsigned short& h, unsigned short& l) {
  __hip_bfloat16 hb = __float2bfloat16(y);
  float hf = __bfloat162float(hb);
  __hip_bfloat16 lb = __float2bfloat16(y - hf);
  union { __hip_bfloat16 b; unsigned short u; } ch, cl;
  ch.b = hb; cl.b = lb;
  h = ch.u; l = cl.u;
}

// ---------------- K1a: row 1/||x|| ----------------
__global__ __launch_bounds__(64) void k_prep_x(const float* __restrict__ x,
                                               float* __restrict__ rnorm) {
  int row = blockIdx.x;
  int lane = threadIdx.x;
  const float* xr = x + (size_t)row * ND;
  float4 v0 = ((const float4*)xr)[lane*2 + 0];
  float4 v1 = ((const float4*)xr)[lane*2 + 1];
  float vals[8] = {v0.x,v0.y,v0.z,v0.w,v1.x,v1.y,v1.z,v1.w};
  float ssq = 0.f;
  #pragma unroll
  for (int k=0;k<8;++k) ssq = fmaf(vals[k], vals[k], ssq);
  #pragma unroll
  for (int off=32; off>0; off>>=1) ssq += __shfl_xor(ssq, off, 64);
  if (lane == 0) rnorm[row] = 1.0f / fmaxf(sqrtf(ssq), 1e-12f);
}

// ---------------- K1b: Wt[o][d] = bf16(W[d][o]); also zero borderline counter ----------------
__global__ __launch_bounds__(1024) void k_prep_w(const float* __restrict__ W,
                                                 __hip_bfloat16* __restrict__ Wt,
                                                 int* __restrict__ counter) {
  __shared__ float tile[32][33];
  int o0 = blockIdx.x*32, d0 = blockIdx.y*32;
  int tx = threadIdx.x, ty = threadIdx.y;
  if (blockIdx.x==0 && blockIdx.y==0 && tx==0 && ty==0) *counter = 0;
  tile[ty][tx] = W[(size_t)(d0+ty)*NO + o0+tx];
  __syncthreads();
  Wt[(size_t)(o0+ty)*ND + d0+tx] = __float2bfloat16(tile[tx][ty]);
}

// ---------------- K2: ht[o][i] = sum_d Wt[o][d]*bf16(x[i][d])  (MFMA bf16) ----------------
__global__ __launch_bounds__(256) void k_gemm_ht(const __hip_bfloat16* __restrict__ Wt,
                                                 const float* __restrict__ xg,
                                                 __hip_bfloat16* __restrict__ ht) {
  __shared__ __hip_bfloat16 At[128*64];
  __shared__ __hip_bfloat16 Bt[128*64];
  int m0 = blockIdx.y*128, n0 = blockIdx.x*128;
  int tid = threadIdx.x;
  int wid = tid>>6, lane = tid&63;
  int wm = (wid>>1)*64, wn = (wid&1)*64;
  f32x4 acc[4][4] = {};
  for (int k0 = 0; k0 < ND; k0 += 64) {
    __syncthreads();
    int r = tid>>3, cb = (tid&7)*8;
    #pragma unroll
    for (int p=0; p<4; ++p) {
      int rr = r + p*32;
      *(uint4*)&At[rr*64 + cb] = *(const uint4*)&Wt[(size_t)(m0+rr)*ND + k0+cb];
      const float* src = &xg[(size_t)(n0+rr)*ND + k0+cb];
      float4 v0 = *(const float4*)src;
      float4 v1 = *(const float4*)(src+4);
      union { unsigned short us[8]; uint4 q; } pk;
      pk.us[0]=f2bs(v0.x); pk.us[1]=f2bs(v0.y); pk.us[2]=f2bs(v0.z); pk.us[3]=f2bs(v0.w);
      pk.us[4]=f2bs(v1.x); pk.us[5]=f2bs(v1.y); pk.us[6]=f2bs(v1.z); pk.us[7]=f2bs(v1.w);
      *(uint4*)&Bt[rr*64 + cb] = pk.q;
    }
    __syncthreads();
    #pragma unroll
    for (int kk=0; kk<64; kk+=32) {
      bf16x8 af[4], bfr[4];
      int rowA = wm + (lane&15);
      int rowB = wn + (lane&15);
      int colk = kk + ((lane>>4)<<3);
      #pragma unroll
      for (int mi=0; mi<4; ++mi) af[mi]  = *(const bf16x8*)&At[(rowA+mi*16)*64 + colk];
      #pragma unroll
      for (int ni=0; ni<4; ++ni) bfr[ni] = *(const bf16x8*)&Bt[(rowB+ni*16)*64 + colk];
      #pragma unroll
      for (int mi=0; mi<4; ++mi)
        #pragma unroll
        for (int ni=0; ni<4; ++ni)
          acc[mi][ni] = __builtin_amdgcn_mfma_f32_16x16x32_bf16(af[mi], bfr[ni], acc[mi][ni], 0,0,0);
    }
  }
  int rbase = (lane>>4)*4, col = lane&15;
  #pragma unroll
  for (int mi=0; mi<4; ++mi)
    #pragma unroll
    for (int ni=0; ni<4; ++ni) {
      int gm = m0 + wm + mi*16 + rbase;
      int gn = n0 + wn + ni*16 + col;
      #pragma unroll
      for (int r2=0; r2<4; ++r2)
        ht[(size_t)(gm+r2)*NROW + gn] = __float2bfloat16(acc[mi][ni][r2]);
    }
}

// ---------------- K3: a_src[i], a_dst[i] from ht columns ----------------
__global__ __launch_bounds__(256) void k_logits(const __hip_bfloat16* __restrict__ ht,
                                                const float* __restrict__ att_src,
                                                const float* __restrict__ att_dst,
                                                float* __restrict__ a_src,
                                                float* __restrict__ a_dst) {
  int i = blockIdx.x*256 + threadIdx.x;
  float s = 0.f, d = 0.f;
  for (int o=0; o<NO; ++o) {
    float hv = __bfloat162float(ht[(size_t)o*NROW + i]);
    s = fmaf(hv, att_src[o], s);
    d = fmaf(hv, att_dst[o], d);
  }
  a_src[i] = s;
  a_dst[i] = d;
}

// ---------------- K4: sim via split-bf16 MFMA, fragment-order LDS (conflict-free) ----------------
// grid (36 = lower-tri 128-tile pairs, 16 batches). C[t][s] = sum_k y[t][k]*y[s][k].
// LDS slot layout: element offset id*8 where id = kb*512 + m*64 + lane,
// holding y[row = m*16 + (lane&15)][k = k0 + kb*32 + (lane>>4)*8 .. +8].
__global__ __launch_bounds__(256) void k_sim_mfma(const float* __restrict__ x,
                                                  const float* __restrict__ rnorm,
                                                  const float* __restrict__ a_src,
                                                  const float* __restrict__ a_dst,
                                                  __hip_bfloat16* __restrict__ E,
                                                  unsigned int* __restrict__ list,
                                                  int* __restrict__ counter) {
  int p = blockIdx.x, b = blockIdx.y;
  int ti = 0;
  while ((ti+1)*(ti+2)/2 <= p) ++ti;
  int tj = p - ti*(ti+1)/2;           // tj <= ti; A rows = dst tile ti, B rows = src tile tj
  __shared__ __hip_bfloat16 Ahi[8192], Alo[8192], Bhi[8192], Blo[8192]; // 64 KiB
  const float* xb_ = x + (size_t)b*NS*ND;
  const float* rn_ = rnorm + b*NS;
  int tid = threadIdx.x;
  int wid = tid>>6, lane = tid&63;
  int wm = (wid>>1)*64, wn = (wid&1)*64;
  f32x4 acc[4][4] = {};
  for (int k0 = 0; k0 < ND; k0 += 64) {
    __syncthreads();
    // FIXED decomposition: id = kb*512 + m*64 + g*16 + r  (matches read side exactly)
    #pragma unroll
    for (int pp=0; pp<4; ++pp) {
      int id = pp*256 + tid;
      int r = id & 15, g = (id>>4)&3, m = (id>>6)&7, kb = id>>9;
      int row = m*16 + r;
      int col = k0 + kb*32 + g*8;
      {
        int grow = ti*128 + row;
        float rn = rn_[grow];
        const float* src = &xb_[(size_t)grow*ND + col];
        float4 v0 = *(const float4*)src;
        float4 v1 = *(const float4*)(src+4);
        float vv[8] = {v0.x,v0.y,v0.z,v0.w,v1.x,v1.y,v1.z,v1.w};
        union { unsigned short us[8]; uint4 q; } ph, pl;
        #pragma unroll
        for (int j=0;j<8;++j) { float y = vv[j]*rn; split_pack(y, ph.us[j], pl.us[j]); }
        *(uint4*)&Ahi[id*8] = ph.q;
        *(uint4*)&Alo[id*8] = pl.q;
      }
      {
        int grow = tj*128 + row;
        float rn = rn_[grow];
        const float* src = &xb_[(size_t)grow*ND + col];
        float4 v0 = *(const float4*)src;
        float4 v1 = *(const float4*)(src+4);
        float vv[8] = {v0.x,v0.y,v0.z,v0.w,v1.x,v1.y,v1.z,v1.w};
        union { unsigned short us[8]; uint4 q; } ph, pl;
        #pragma unroll
        for (int j=0;j<8;++j) { float y = vv[j]*rn; split_pack(y, ph.us[j], pl.us[j]); }
        *(uint4*)&Bhi[id*8] = ph.q;
        *(uint4*)&Blo[id*8] = pl.q;
      }
    }
    __syncthreads();
    #pragma unroll
    for (int kb=0; kb<2; ++kb) {
      bf16x8 ah[4], al[4], bh[4], bl[4];
      #pragma unroll
      for (int q=0; q<4; ++q) {
        int aoff = ((kb*8 + (wm>>4) + q)*64 + lane)*8;
        ah[q] = *(const bf16x8*)&Ahi[aoff];
        al[q] = *(const bf16x8*)&Alo[aoff];
        int boff = ((kb*8 + (wn>>4) + q)*64 + lane)*8;
        bh[q] = *(const bf16x8*)&Bhi[boff];
        bl[q] = *(const bf16x8*)&Blo[boff];
      }
      #pragma unroll
      for (int mi=0; mi<4; ++mi)
        #pragma unroll
        for (int ni=0; ni<4; ++ni) {
          acc[mi][ni] = __builtin_amdgcn_mfma_f32_16x16x32_bf16(ah[mi], bh[ni], acc[mi][ni], 0,0,0);
          acc[mi][ni] = __builtin_amdgcn_mfma_f32_16x16x32_bf16(ah[mi], bl[ni], acc[mi][ni], 0,0,0);
          acc[mi][ni] = __builtin_amdgcn_mfma_f32_16x16x32_bf16(al[mi], bh[ni], acc[mi][ni], 0,0,0);
        }
    }
  }
  int rbase = (lane>>4)*4, colL = lane&15;
  #pragma unroll
  for (int mi=0; mi<4; ++mi) {
    #pragma unroll
    for (int r2=0; r2<4; ++r2) {
      int t_g = ti*128 + wm + mi*16 + rbase + r2;
      int git = b*NS + t_g;
      float adv = a_dst[git];
      __hip_bfloat16* Erow = E + (size_t)git*NS;
      #pragma unroll
      for (int ni=0; ni<4; ++ni) {
        int s_g = tj*128 + wn + ni*16 + colL;
        int gis = b*NS + s_g;
        float sim = acc[mi][ni][r2];
        float v = adv + a_src[gis];
        float e = (v > 0.f) ? v : 0.2f*v;
        bool edge = (s_g == t_g) || (s_g < t_g && sim > 0.9f);
        if (s_g < t_g && fabsf(sim - 0.9f) <= SIM_BAND) {
          int idx = atomicAdd(counter, 1);
          if (idx < LIST_CAP) list[idx] = ((unsigned)b<<20) | ((unsigned)t_g<<10) | (unsigned)s_g;
        }
        Erow[s_g] = edge ? __float2bfloat16(e) : __float2bfloat16(-INFINITY);
      }
    }
  }
}

// ---------------- K4b: exact f32 recheck of borderline pairs ----------------
__global__ __launch_bounds__(256) void k_recheck(const float* __restrict__ x,
                                                 const float* __restrict__ rnorm,
                                                 const float* __restrict__ a_src,
                                                 const float* __restrict__ a_dst,
                                                 __hip_bfloat16* __restrict__ E,
                                                 const unsigned int* __restrict__ list,
                                                 const int* __restrict__ counter) {
  int n = *counter;
  if (n > LIST_CAP) n = LIST_CAP;
  int gid = blockIdx.x*256 + threadIdx.x;
  for (int i = gid; i < n; i += 256*256) {
    unsigned v = list[i];
    int b = v>>20, t = (v>>10)&1023, s = v&1023;
    const float* xt = x + ((size_t)(b*NS + t))*ND;
    const float* xs = x + ((size_t)(b*NS + s))*ND;
    float4 a4 = {0.f,0.f,0.f,0.f};
    for (int k=0; k<ND; k+=4) {
      float4 av = *(const float4*)&xt[k];
      float4 bv = *(const float4*)&xs[k];
      a4.x = fmaf(av.x,bv.x,a4.x); a4.y = fmaf(av.y,bv.y,a4.y);
      a4.z = fmaf(av.z,bv.z,a4.z); a4.w = fmaf(av.w,bv.w,a4.w);
    }
    float dot = (a4.x+a4.y)+(a4.z+a4.w);
    float sim = dot * rnorm[b*NS+t] * rnorm[b*NS+s];
    float vv = a_dst[b*NS+t] + a_src[b*NS+s];
    float e = (vv > 0.f) ? vv : 0.2f*vv;
    E[((size_t)(b*NS+t))*NS + s] = (sim > 0.9f) ? __float2bfloat16(e)
                                                : __float2bfloat16(-INFINITY);
  }
}

// ---------------- K5: per-row masked softmax in place, zero-fill to 128-boundary ----------------
__global__ __launch_bounds__(256) void k_softmax(__hip_bfloat16* __restrict__ E) {
  int rowid = blockIdx.x;
  int t = rowid & (NS-1);
  __hip_bfloat16* Erow = E + (size_t)rowid * NS;
  int tid = threadIdx.x;
  int n = t + 1;
  float v[4];
  float lm = -INFINITY;
  #pragma unroll
  for (int k=0;k<4;++k) {
    int s = tid + k*256;
    v[k] = (s < n) ? __bfloat162float(Erow[s]) : -INFINITY;
    lm = fmaxf(lm, v[k]);
  }
  __shared__ float red1[4];
  __shared__ float red2[4];
  #pragma unroll
  for (int off=32; off>0; off>>=1) lm = fmaxf(lm, __shfl_xor(lm, off, 64));
  int wid = tid>>6, lane = tid&63;
  if (lane==0) red1[wid] = lm;
  __syncthreads();
  float m = fmaxf(fmaxf(red1[0],red1[1]), fmaxf(red1[2],red1[3]));
  float ls = 0.f;
  #pragma unroll
  for (int k=0;k<4;++k) {
    int s = tid + k*256;
    if (s < n) ls += __expf(v[k] - m);
  }
  #pragma unroll
  for (int off=32; off>0; off>>=1) ls += __shfl_xor(ls, off, 64);
  if (lane==0) red2[wid] = ls;
  __syncthreads();
  float l = red2[0]+red2[1]+red2[2]+red2[3];
  float inv = 1.0f / l;
  #pragma unroll
  for (int k=0;k<4;++k) {
    int s = tid + k*256;
    if (s < n) Erow[s] = __float2bfloat16(__expf(v[k] - m) * inv);
  }
  int end = ((t >> 7) + 1) << 7;
  for (int s = n + tid; s < end; s += 256) Erow[s] = __float2bfloat16(0.0f);
}

// ---------------- K6: out = relu(P @ h + bias), causal K extent ----------------
__global__ __launch_bounds__(256) void k_pv(const __hip_bfloat16* __restrict__ P,
                                            const __hip_bfloat16* __restrict__ ht,
                                            const float* __restrict__ bias,
                                            float* __restrict__ out) {
  int nt = blockIdx.x, mt = blockIdx.y, b = blockIdx.z;
  int m0 = mt*128, n0 = nt*128;
  int Kext = (mt+1)*128;
  __shared__ __hip_bfloat16 At[128*64];
  __shared__ __hip_bfloat16 Bt[128*64];
  const __hip_bfloat16* Pb = P + (size_t)b*NS*NS;
  int tid = threadIdx.x;
  int wid = tid>>6, lane = tid&63;
  int wm = (wid>>1)*64, wn = (wid&1)*64;
  f32x4 acc[4][4] = {};
  for (int k0 = 0; k0 < Kext; k0 += 64) {
    __syncthreads();
    int r = tid>>3, cb = (tid&7)*8;
    #pragma unroll
    for (int p=0; p<4; ++p) {
      int rr = r + p*32;
      *(uint4*)&At[rr*64 + cb] = *(const uint4*)&Pb[(size_t)(m0+rr)*NS + k0+cb];
      *(uint4*)&Bt[rr*64 + cb] = *(const uint4*)&ht[(size_t)(n0+rr)*NROW + b*NS + k0+cb];
    }
    __syncthreads();
    #pragma unroll
    for (int kk=0; kk<64; kk+=32) {
      bf16x8 af[4], bfr[4];
      int rowA = wm + (lane&15);
      int rowB = wn + (lane&15);
      int colk = kk + ((lane>>4)<<3);
      #pragma unroll
      for (int mi=0; mi<4; ++mi) af[mi]  = *(const bf16x8*)&At[(rowA+mi*16)*64 + colk];
      #pragma unroll
      for (int ni=0; ni<4; ++ni) bfr[ni] = *(const bf16x8*)&Bt[(rowB+ni*16)*64 + colk];
      #pragma unroll
      for (int mi=0; mi<4; ++mi)
        #pragma unroll
        for (int ni=0; ni<4; ++ni)
          acc[mi][ni] = __builtin_amdgcn_mfma_f32_16x16x32_bf16(af[mi], bfr[ni], acc[mi][ni], 0,0,0);
    }
  }
  int rbase = (lane>>4)*4, col = lane&15;
  #pragma unroll
  for (int mi=0; mi<4; ++mi)
    #pragma unroll
    for (int ni=0; ni<4; ++ni) {
      int gm = m0 + wm + mi*16 + rbase;
      int gn = n0 + wn + ni*16 + col;
      float bv = bias[gn];
      #pragma unroll
      for (int r2=0; r2<4; ++r2)
        out[((size_t)b*NS + gm + r2)*NO + gn] = fmaxf(acc[mi][ni][r2] + bv, 0.0f);
    }
}

extern "C" void kernel_launch(void* const* d_in, const int* in_sizes, int n_in,
                              void* d_out, int out_size, void* d_ws, size_t ws_size,
                              hipStream_t stream) {
  (void)in_sizes; (void)n_in; (void)out_size; (void)ws_size;
  const float* x       = (const float*)d_in[0];
  const float* W       = (const float*)d_in[1];
  const float* att_src = (const float*)d_in[2];
  const float* att_dst = (const float*)d_in[3];
  const float* bias    = (const float*)d_in[4];
  float* out = (float*)d_out;

  char* ws = (char*)d_ws;
  __hip_bfloat16* Wt    = (__hip_bfloat16*)(ws + 0);           //    524,288 B
  __hip_bfloat16* ht    = (__hip_bfloat16*)(ws + 524288);      // 16,777,216 B
  float*          rnorm = (float*)        (ws + 17301504);     //     65,536 B
  float*          a_src = (float*)        (ws + 17367040);     //     65,536 B
  float*          a_dst = (float*)        (ws + 17432576);     //     65,536 B
  int*            cnt   = (int*)          (ws + 17498112);     //         64 B
  unsigned int*   list  = (unsigned int*) (ws + 17498176);     //  8,388,608 B
  __hip_bfloat16* E     = (__hip_bfloat16*)(ws + 25886784);    // 33,554,432 B (end ~56.7 MB)

  k_prep_x  <<<dim3(NROW),   dim3(64),    0, stream>>>(x, rnorm);
  k_prep_w  <<<dim3(16,16),  dim3(32,32), 0, stream>>>(W, Wt, cnt);
  k_gemm_ht <<<dim3(128,4),  dim3(256),   0, stream>>>(Wt, x, ht);
  k_logits  <<<dim3(64),     dim3(256),   0, stream>>>(ht, att_src, att_dst, a_src, a_dst);
  k_sim_mfma<<<dim3(36,16),  dim3(256),   0, stream>>>(x, rnorm, a_src, a_dst, E, list, cnt);
  k_recheck <<<dim3(256),    dim3(256),   0, stream>>>(x, rnorm, a_src, a_dst, E, list, cnt);
  k_softmax <<<dim3(NROW),   dim3(256),   0, stream>>>(E);
  k_pv      <<<dim3(4,8,16), dim3(256),   0, stream>>>(E, ht, bias, out);
}

// Round 4
// 192.474 us; speedup vs baseline: 1.8847x; 1.2199x over previous
//
#include <hip/hip_runtime.h>
#include <hip/hip_bf16.h>
#include <stdint.h>

#define NB 16
#define NS 1024
#define ND 512
#define NO 512
#define NROW (NB*NS)   // 16384
#define SIM_BAND 2e-3f
#define LIST_CAP 1048576

typedef float f32x4 __attribute__((ext_vector_type(4)));
typedef __bf16 bf16x8 __attribute__((ext_vector_type(8)));

#define GLOAD_LDS16(g, l) __builtin_amdgcn_global_load_lds( \
    (const __attribute__((address_space(1))) void*)(g), \
    (__attribute__((address_space(3))) void*)(l), 16, 0, 0)

__device__ inline unsigned short f2bs(float f) {
  union { __hip_bfloat16 h; unsigned short u; } c;
  c.h = __float2bfloat16(f);
  return c.u;
}

// ---------------- K0: rnorm + trunc-split y -> yhi/ylo in fragment-order layout ----------------
// Layout: element offset ((b*8+t)*8 + k0c)*8192 + id*8, id = kb*512 + m*64 + g*16 + r
// holds y[row=t*128+m*16+r][col=k0c*64+kb*32+g*8 .. +8] (normalized), hi/lo bf16.
__global__ __launch_bounds__(256) void k_prep_y(const float* __restrict__ x,
                                                __hip_bfloat16* __restrict__ yhi,
                                                __hip_bfloat16* __restrict__ ylo,
                                                float* __restrict__ rnorm,
                                                int* __restrict__ counter) {
  int blk = blockIdx.x;            // 0..127: b = blk>>3, t = blk&7
  int tid = threadIdx.x;
  if (blk == 0 && tid == 0) *counter = 0;
  int b = blk>>3, t = blk&7;
  int row = tid>>1, half = tid&1;
  const float* xr = x + ((size_t)(b*NS) + t*128 + row)*ND + half*256;
  float ssq = 0.f;
  for (int c = 0; c < 256; c += 4) {
    float4 v = *(const float4*)&xr[c];
    ssq = fmaf(v.x,v.x, fmaf(v.y,v.y, fmaf(v.z,v.z, fmaf(v.w,v.w, ssq))));
  }
  ssq += __shfl_xor(ssq, 1, 64);
  float rn = 1.0f / fmaxf(sqrtf(ssq), 1e-12f);
  if (half == 0) rnorm[b*NS + t*128 + row] = rn;
  int m = row>>4, r = row&15;
  size_t tilebase = ((size_t)(b*8+t))*65536;
  for (int gc = 0; gc < 32; ++gc) {
    int col = half*256 + gc*8;
    int k0c = col>>6, cc = col&63, kb = cc>>5, g = (cc>>3)&3;
    int id = kb*512 + m*64 + g*16 + r;
    size_t off = tilebase + (size_t)k0c*8192 + id*8;
    float4 v0 = *(const float4*)&xr[gc*8];
    float4 v1 = *(const float4*)&xr[gc*8+4];
    float vv[8] = {v0.x,v0.y,v0.z,v0.w,v1.x,v1.y,v1.z,v1.w};
    union { unsigned short us[8]; uint4 q; } ph, pl;
    #pragma unroll
    for (int j = 0; j < 8; ++j) {
      float y = vv[j]*rn;
      unsigned yb = __float_as_uint(y);
      float hf = __uint_as_float(yb & 0xFFFF0000u);
      float lf = y - hf;                       // exact
      ph.us[j] = (unsigned short)(yb >> 16);
      pl.us[j] = (unsigned short)(__float_as_uint(lf) >> 16);
    }
    *(uint4*)&yhi[off] = ph.q;
    *(uint4*)&ylo[off] = pl.q;
  }
}

// ---------------- K4: sim via split-bf16 MFMA, global_load_lds staging -> byte mask ----------------
__global__ __launch_bounds__(256) void k_sim_mfma(const __hip_bfloat16* __restrict__ yhi,
                                                  const __hip_bfloat16* __restrict__ ylo,
                                                  uint8_t* __restrict__ Mmask,
                                                  unsigned int* __restrict__ list,
                                                  int* __restrict__ counter) {
  int bid = blockIdx.x;
  int swz = (bid & 7)*72 + (bid >> 3);      // bijective: 576 = 8*72; XCD-local batches
  int b = swz / 36, p = swz - b*36;
  int ti = 0;
  while ((ti+1)*(ti+2)/2 <= p) ++ti;
  int tj = p - ti*(ti+1)/2;                 // tj <= ti
  __shared__ __hip_bfloat16 Ahi[8192], Alo[8192], Bhi[8192], Blo[8192];
  int tid = threadIdx.x, wid = tid>>6, lane = tid&63;
  int wm = (wid>>1)*64, wn = (wid&1)*64;
  bool diag = (ti == tj);
  const __hip_bfloat16* Bh = diag ? Ahi : Bhi;
  const __hip_bfloat16* Bl = diag ? Alo : Blo;
  f32x4 acc[4][4] = {};
  for (int k0c = 0; k0c < 8; ++k0c) {
    __syncthreads();
    size_t abase = ((size_t)((b*8+ti)*8 + k0c))*8192 + wid*2048 + lane*8;
    size_t bbase = ((size_t)((b*8+tj)*8 + k0c))*8192 + wid*2048 + lane*8;
    int lb = wid*2048;
    #pragma unroll
    for (int i = 0; i < 4; ++i) {
      GLOAD_LDS16(yhi + abase + i*512, &Ahi[lb + i*512]);
      GLOAD_LDS16(ylo + abase + i*512, &Alo[lb + i*512]);
    }
    if (!diag) {
      #pragma unroll
      for (int i = 0; i < 4; ++i) {
        GLOAD_LDS16(yhi + bbase + i*512, &Bhi[lb + i*512]);
        GLOAD_LDS16(ylo + bbase + i*512, &Blo[lb + i*512]);
      }
    }
    __syncthreads();   // compiler drains vmcnt before barrier
    #pragma unroll
    for (int kb = 0; kb < 2; ++kb) {
      bf16x8 ah[4], al[4], bh[4], bl[4];
      #pragma unroll
      for (int q = 0; q < 4; ++q) {
        int aoff = ((kb*8 + (wm>>4) + q)*64 + lane)*8;
        ah[q] = *(const bf16x8*)&Ahi[aoff];
        al[q] = *(const bf16x8*)&Alo[aoff];
        int boff = ((kb*8 + (wn>>4) + q)*64 + lane)*8;
        bh[q] = *(const bf16x8*)&Bh[boff];
        bl[q] = *(const bf16x8*)&Bl[boff];
      }
      #pragma unroll
      for (int mi = 0; mi < 4; ++mi)
        #pragma unroll
        for (int ni = 0; ni < 4; ++ni) {
          acc[mi][ni] = __builtin_amdgcn_mfma_f32_16x16x32_bf16(ah[mi], bh[ni], acc[mi][ni], 0,0,0);
          acc[mi][ni] = __builtin_amdgcn_mfma_f32_16x16x32_bf16(ah[mi], bl[ni], acc[mi][ni], 0,0,0);
          acc[mi][ni] = __builtin_amdgcn_mfma_f32_16x16x32_bf16(al[mi], bh[ni], acc[mi][ni], 0,0,0);
        }
    }
  }
  int rbase = (lane>>4)*4, colL = lane&15;
  #pragma unroll
  for (int mi = 0; mi < 4; ++mi) {
    #pragma unroll
    for (int r2 = 0; r2 < 4; ++r2) {
      int t_g = ti*128 + wm + mi*16 + rbase + r2;
      int git = b*NS + t_g;
      uint8_t* Mrow = Mmask + (size_t)git*NS;
      #pragma unroll
      for (int ni = 0; ni < 4; ++ni) {
        int s_g = tj*128 + wn + ni*16 + colL;
        if (s_g > t_g) continue;
        float sim = acc[mi][ni][r2];
        bool edge = (s_g == t_g) || (sim > 0.9f);
        if (s_g < t_g && fabsf(sim - 0.9f) <= SIM_BAND) {
          int idx = atomicAdd(counter, 1);
          if (idx < LIST_CAP) list[idx] = ((unsigned)b<<20) | ((unsigned)t_g<<10) | (unsigned)s_g;
        }
        Mrow[s_g] = edge ? 1 : 0;
      }
    }
  }
}

// ---------------- K4b: exact f32 recheck of borderline pairs -> fix mask ----------------
__global__ __launch_bounds__(256) void k_recheck(const float* __restrict__ x,
                                                 const float* __restrict__ rnorm,
                                                 uint8_t* __restrict__ Mmask,
                                                 const unsigned int* __restrict__ list,
                                                 const int* __restrict__ counter) {
  int n = *counter;
  if (n > LIST_CAP) n = LIST_CAP;
  int gid = blockIdx.x*256 + threadIdx.x;
  for (int i = gid; i < n; i += 256*256) {
    unsigned v = list[i];
    int b = v>>20, t = (v>>10)&1023, s = v&1023;
    const float* xt = x + ((size_t)(b*NS + t))*ND;
    const float* xs = x + ((size_t)(b*NS + s))*ND;
    float4 a4 = {0.f,0.f,0.f,0.f};
    for (int k = 0; k < ND; k += 4) {
      float4 av = *(const float4*)&xt[k];
      float4 bv = *(const float4*)&xs[k];
      a4.x = fmaf(av.x,bv.x,a4.x); a4.y = fmaf(av.y,bv.y,a4.y);
      a4.z = fmaf(av.z,bv.z,a4.z); a4.w = fmaf(av.w,bv.w,a4.w);
    }
    float dot = (a4.x+a4.y)+(a4.z+a4.w);
    float sim = dot * rnorm[b*NS+t] * rnorm[b*NS+s];
    Mmask[((size_t)(b*NS+t))*NS + s] = (sim > 0.9f) ? 1 : 0;
  }
}

// ---------------- K1b: Wt[o][d] = bf16(W[d][o]) ----------------
__global__ __launch_bounds__(1024) void k_prep_w(const float* __restrict__ W,
                                                 __hip_bfloat16* __restrict__ Wt) {
  __shared__ float tile[32][33];
  int o0 = blockIdx.x*32, d0 = blockIdx.y*32;
  int tx = threadIdx.x, ty = threadIdx.y;
  tile[ty][tx] = W[(size_t)(d0+ty)*NO + o0+tx];
  __syncthreads();
  Wt[(size_t)(o0+ty)*ND + d0+tx] = __float2bfloat16(tile[tx][ty]);
}

// ---------------- K2: ht[o][i] = sum_d Wt[o][d]*bf16(x[i][d])  (MFMA, XOR-swizzled LDS) ----------------
__global__ __launch_bounds__(256) void k_gemm_ht(const __hip_bfloat16* __restrict__ Wt,
                                                 const float* __restrict__ xg,
                                                 __hip_bfloat16* __restrict__ ht) {
  __shared__ __hip_bfloat16 At[128*64];
  __shared__ __hip_bfloat16 Bt[128*64];
  int m0 = blockIdx.y*128, n0 = blockIdx.x*128;
  int tid = threadIdx.x;
  int wid = tid>>6, lane = tid&63;
  int wm = (wid>>1)*64, wn = (wid&1)*64;
  f32x4 acc[4][4] = {};
  for (int k0 = 0; k0 < ND; k0 += 64) {
    __syncthreads();
    int r = tid>>3, cb = (tid&7)*8;
    #pragma unroll
    for (int p = 0; p < 4; ++p) {
      int R = r + p*32;
      int cbs = cb ^ ((R&7)<<3);
      *(uint4*)&At[R*64 + cbs] = *(const uint4*)&Wt[(size_t)(m0+R)*ND + k0+cb];
      const float* src = &xg[(size_t)(n0+R)*ND + k0+cb];
      float4 v0 = *(const float4*)src;
      float4 v1 = *(const float4*)(src+4);
      union { unsigned short us[8]; uint4 q; } pk;
      pk.us[0]=f2bs(v0.x); pk.us[1]=f2bs(v0.y); pk.us[2]=f2bs(v0.z); pk.us[3]=f2bs(v0.w);
      pk.us[4]=f2bs(v1.x); pk.us[5]=f2bs(v1.y); pk.us[6]=f2bs(v1.z); pk.us[7]=f2bs(v1.w);
      *(uint4*)&Bt[R*64 + cbs] = pk.q;
    }
    __syncthreads();
    #pragma unroll
    for (int kk = 0; kk < 64; kk += 32) {
      bf16x8 af[4], bfr[4];
      int colk = kk + ((lane>>4)<<3);
      #pragma unroll
      for (int mi = 0; mi < 4; ++mi) {
        int row = wm + (lane&15) + mi*16;
        af[mi] = *(const bf16x8*)&At[row*64 + (colk ^ ((row&7)<<3))];
      }
      #pragma unroll
      for (int ni = 0; ni < 4; ++ni) {
        int row = wn + (lane&15) + ni*16;
        bfr[ni] = *(const bf16x8*)&Bt[row*64 + (colk ^ ((row&7)<<3))];
      }
      #pragma unroll
      for (int mi = 0; mi < 4; ++mi)
        #pragma unroll
        for (int ni = 0; ni < 4; ++ni)
          acc[mi][ni] = __builtin_amdgcn_mfma_f32_16x16x32_bf16(af[mi], bfr[ni], acc[mi][ni], 0,0,0);
    }
  }
  int rbase = (lane>>4)*4, col = lane&15;
  #pragma unroll
  for (int mi = 0; mi < 4; ++mi)
    #pragma unroll
    for (int ni = 0; ni < 4; ++ni) {
      int gm = m0 + wm + mi*16 + rbase;
      int gn = n0 + wn + ni*16 + col;
      #pragma unroll
      for (int r2 = 0; r2 < 4; ++r2)
        ht[(size_t)(gm+r2)*NROW + gn] = __float2bfloat16(acc[mi][ni][r2]);
    }
}

// ---------------- K3: a_src[i], a_dst[i] from ht columns ----------------
__global__ __launch_bounds__(256) void k_logits(const __hip_bfloat16* __restrict__ ht,
                                                const float* __restrict__ att_src,
                                                const float* __restrict__ att_dst,
                                                float* __restrict__ a_src,
                                                float* __restrict__ a_dst) {
  int i = blockIdx.x*256 + threadIdx.x;
  float s = 0.f, d = 0.f;
  for (int o = 0; o < NO; ++o) {
    float hv = __bfloat162float(ht[(size_t)o*NROW + i]);
    s = fmaf(hv, att_src[o], s);
    d = fmaf(hv, att_dst[o], d);
  }
  a_src[i] = s;
  a_dst[i] = d;
}

// ---------------- K5: masked softmax from byte mask -> P (bf16), zero-fill to 128 ----------------
__global__ __launch_bounds__(256) void k_softmax(const uint8_t* __restrict__ Mmask,
                                                 const float* __restrict__ a_src,
                                                 const float* __restrict__ a_dst,
                                                 __hip_bfloat16* __restrict__ P) {
  int rowid = blockIdx.x;
  int t = rowid & (NS-1);
  int b = rowid >> 10;
  const uint8_t* Mrow = Mmask + (size_t)rowid * NS;
  __hip_bfloat16* Prow = P + (size_t)rowid * NS;
  const float* as = a_src + b*NS;
  float adv = a_dst[rowid];
  int tid = threadIdx.x;
  int n = t + 1;
  float v[4];
  float lm = -INFINITY;
  #pragma unroll
  for (int k = 0; k < 4; ++k) {
    int s = tid + k*256;
    v[k] = -INFINITY;
    if (s < n && Mrow[s]) {
      float vv = adv + as[s];
      v[k] = (vv > 0.f) ? vv : 0.2f*vv;
    }
    lm = fmaxf(lm, v[k]);
  }
  __shared__ float red1[4];
  __shared__ float red2[4];
  #pragma unroll
  for (int off = 32; off > 0; off >>= 1) lm = fmaxf(lm, __shfl_xor(lm, off, 64));
  int wid = tid>>6, lane = tid&63;
  if (lane == 0) red1[wid] = lm;
  __syncthreads();
  float m = fmaxf(fmaxf(red1[0],red1[1]), fmaxf(red1[2],red1[3]));
  float ls = 0.f;
  #pragma unroll
  for (int k = 0; k < 4; ++k) if (v[k] > -INFINITY) ls += __expf(v[k] - m);
  #pragma unroll
  for (int off = 32; off > 0; off >>= 1) ls += __shfl_xor(ls, off, 64);
  if (lane == 0) red2[wid] = ls;
  __syncthreads();
  float l = red2[0]+red2[1]+red2[2]+red2[3];
  float inv = 1.0f / l;
  #pragma unroll
  for (int k = 0; k < 4; ++k) {
    int s = tid + k*256;
    if (s < n) Prow[s] = __float2bfloat16((v[k] > -INFINITY) ? __expf(v[k]-m)*inv : 0.0f);
  }
  int end = ((t >> 7) + 1) << 7;
  for (int s = n + tid; s < end; s += 256) Prow[s] = __float2bfloat16(0.0f);
}

// ---------------- K6: out = relu(P @ h + bias), causal K extent, XOR-swizzled LDS ----------------
__global__ __launch_bounds__(256) void k_pv(const __hip_bfloat16* __restrict__ P,
                                            const __hip_bfloat16* __restrict__ ht,
                                            const float* __restrict__ bias,
                                            float* __restrict__ out) {
  int nt = blockIdx.x, mt = blockIdx.y, b = blockIdx.z;
  int m0 = mt*128, n0 = nt*128;
  int Kext = (mt+1)*128;
  __shared__ __hip_bfloat16 At[128*64];
  __shared__ __hip_bfloat16 Bt[128*64];
  const __hip_bfloat16* Pb = P + (size_t)b*NS*NS;
  int tid = threadIdx.x;
  int wid = tid>>6, lane = tid&63;
  int wm = (wid>>1)*64, wn = (wid&1)*64;
  f32x4 acc[4][4] = {};
  for (int k0 = 0; k0 < Kext; k0 += 64) {
    __syncthreads();
    int r = tid>>3, cb = (tid&7)*8;
    #pragma unroll
    for (int p = 0; p < 4; ++p) {
      int R = r + p*32;
      int cbs = cb ^ ((R&7)<<3);
      *(uint4*)&At[R*64 + cbs] = *(const uint4*)&Pb[(size_t)(m0+R)*NS + k0+cb];
      *(uint4*)&Bt[R*64 + cbs] = *(const uint4*)&ht[(size_t)(n0+R)*NROW + b*NS + k0+cb];
    }
    __syncthreads();
    #pragma unroll
    for (int kk = 0; kk < 64; kk += 32) {
      bf16x8 af[4], bfr[4];
      int colk = kk + ((lane>>4)<<3);
      #pragma unroll
      for (int mi = 0; mi < 4; ++mi) {
        int row = wm + (lane&15) + mi*16;
        af[mi] = *(const bf16x8*)&At[row*64 + (colk ^ ((row&7)<<3))];
      }
      #pragma unroll
      for (int ni = 0; ni < 4; ++ni) {
        int row = wn + (lane&15) + ni*16;
        bfr[ni] = *(const bf16x8*)&Bt[row*64 + (colk ^ ((row&7)<<3))];
      }
      #pragma unroll
      for (int mi = 0; mi < 4; ++mi)
        #pragma unroll
        for (int ni = 0; ni < 4; ++ni)
          acc[mi][ni] = __builtin_amdgcn_mfma_f32_16x16x32_bf16(af[mi], bfr[ni], acc[mi][ni], 0,0,0);
    }
  }
  int rbase = (lane>>4)*4, col = lane&15;
  #pragma unroll
  for (int mi = 0; mi < 4; ++mi)
    #pragma unroll
    for (int ni = 0; ni < 4; ++ni) {
      int gm = m0 + wm + mi*16 + rbase;
      int gn = n0 + wn + ni*16 + col;
      float bv = bias[gn];
      #pragma unroll
      for (int r2 = 0; r2 < 4; ++r2)
        out[((size_t)b*NS + gm + r2)*NO + gn] = fmaxf(acc[mi][ni][r2] + bv, 0.0f);
    }
}

extern "C" void kernel_launch(void* const* d_in, const int* in_sizes, int n_in,
                              void* d_out, int out_size, void* d_ws, size_t ws_size,
                              hipStream_t stream) {
  (void)in_sizes; (void)n_in; (void)out_size; (void)ws_size;
  const float* x       = (const float*)d_in[0];
  const float* W       = (const float*)d_in[1];
  const float* att_src = (const float*)d_in[2];
  const float* att_dst = (const float*)d_in[3];
  const float* bias    = (const float*)d_in[4];
  float* out = (float*)d_out;

  char* ws = (char*)d_ws;
  // Lifetime-aliased map (total 67,829,760 B = proven ws floor):
  __hip_bfloat16* yhi   = (__hip_bfloat16*)(ws + 0);          // 16 MB  [prep_y..sim]
  __hip_bfloat16* ylo   = (__hip_bfloat16*)(ws + 16777216);   // 16 MB  [prep_y..sim]
  __hip_bfloat16* P     = (__hip_bfloat16*)(ws + 0);          // 32 MB  [softmax..pv]  (aliases yhi/ylo)
  int*            cnt   = (int*)          (ws + 33554432);    //        [prep_y..recheck]
  unsigned int*   list  = (unsigned int*) (ws + 33554448);    //  4 MB  [sim..recheck]
  __hip_bfloat16* ht    = (__hip_bfloat16*)(ws + 33554432);   // 16 MB  [gemm_ht..pv] (aliases cnt/list)
  uint8_t*        Mmask = (uint8_t*)      (ws + 50331648);    // 16 MB  [sim..softmax]
  __hip_bfloat16* Wt    = (__hip_bfloat16*)(ws + 67108864);   // 512 KB [prep_w..gemm_ht]
  float*          rnorm = (float*)        (ws + 67633152);    // 64 KB  [prep_y..recheck]
  float*          a_src = (float*)        (ws + 67698688);    // 64 KB  [logits..softmax]
  float*          a_dst = (float*)        (ws + 67764224);    // 64 KB  [logits..softmax]

  k_prep_y  <<<dim3(128),    dim3(256),   0, stream>>>(x, yhi, ylo, rnorm, cnt);
  k_sim_mfma<<<dim3(576),    dim3(256),   0, stream>>>(yhi, ylo, Mmask, list, cnt);
  k_recheck <<<dim3(256),    dim3(256),   0, stream>>>(x, rnorm, Mmask, list, cnt);
  k_prep_w  <<<dim3(16,16),  dim3(32,32), 0, stream>>>(W, Wt);
  k_gemm_ht <<<dim3(128,4),  dim3(256),   0, stream>>>(Wt, x, ht);
  k_logits  <<<dim3(64),     dim3(256),   0, stream>>>(ht, att_src, att_dst, a_src, a_dst);
  k_softmax <<<dim3(NROW),   dim3(256),   0, stream>>>(Mmask, a_src, a_dst, P);
  k_pv      <<<dim3(4,8,16), dim3(256),   0, stream>>>(P, ht, bias, out);
}